// Round 4
// baseline (405.602 us; speedup 1.0000x reference)
//
#include <hip/hip_runtime.h>

// LightGCN 3-layer propagation. out layout: [4, N_NODES, DIM] f32.
//   layer 0 = embeddings (copy); layer l = SpMM(layer l-1).
//
// Build-stage history:
//  R4: node-granular scatter, dst-range by blockIdx%8. WRITE 77->73 MB only.
//  R5: bucket streams -> 755us. 768 returning atomics/addr serialized at the
//      device coherence point (~410ns each). Rule: multiplicity <= tens.
//  R6: NT edge streams. WRITE 73->54.6, dur 66->64. Residency fixed, merge
//      still broken -> the blockIdx%8 ~ XCD assumption is the suspect.
//  R7 (this round):
//    - scatter: bind range = PHYSICAL XCD via s_getreg(HW_REG_XCC_ID), slices
//      pulled from a per-range ticket (persistent blocks). Guarantees all
//      writes to a range's 1.2MB pairs region come from ONE L2, any mapping.
//    - hist: atomics execute at the memory-side coherence point regardless of
//      issuing XCD -> range replication was pure waste. Single int4 pass.
//    - scan3 seeds cur=off; scatter needs no off gather.

#define N_NODES 100000
#define DIM 64
#define SCAN_CHUNK 1024   // elements scanned per block in scan1 (256 thr x 4)

#define NR 8                              // dst ranges = physical XCDs
#define RSIZE ((N_NODES + NR - 1) / NR)   // 12500 nodes per range
#define SLICES 256                        // edge slices per range

typedef int   vint4   __attribute__((ext_vector_type(4)));
typedef float vfloat4 __attribute__((ext_vector_type(4)));

__device__ __forceinline__ int xcd_id() {
    int x;
    asm volatile("s_getreg_b32 %0, hwreg(HW_REG_XCC_ID)" : "=s"(x));
    return x & (NR - 1);
}

// ---------------- CSR build ----------------

// Single-pass vectorized histogram. Device-scope atomics resolve at the
// memory-side coherence point; issuing XCD is irrelevant. ~12/addr: fine.
__global__ void hist_kernel(const int* __restrict__ edst, int* __restrict__ deg, int E) {
    int i = blockIdx.x * blockDim.x + threadIdx.x;
    int nv = E >> 2;
    if (i < nv) {
        vint4 d = __builtin_nontemporal_load(((const vint4*)edst) + i);
        atomicAdd(&deg[d[0]], 1);
        atomicAdd(&deg[d[1]], 1);
        atomicAdd(&deg[d[2]], 1);
        atomicAdd(&deg[d[3]], 1);
    }
    if (i == 0) {
        for (int e = nv << 2; e < E; ++e) atomicAdd(&deg[edst[e]], 1);
    }
}

// Per-block exclusive scan over chunks of 1024; emits per-block totals.
__global__ void scan1_kernel(const int* __restrict__ deg, int* __restrict__ off,
                             int* __restrict__ bsum, int n) {
    __shared__ int sdata[256];
    int tid = threadIdx.x;
    int base = blockIdx.x * SCAN_CHUNK + tid * 4;
    int v[4];
    #pragma unroll
    for (int i = 0; i < 4; ++i) v[i] = (base + i < n) ? deg[base + i] : 0;
    int tsum = v[0] + v[1] + v[2] + v[3];
    sdata[tid] = tsum;
    __syncthreads();
    for (int d = 1; d < 256; d <<= 1) {
        int t = (tid >= d) ? sdata[tid - d] : 0;
        __syncthreads();
        sdata[tid] += t;
        __syncthreads();
    }
    int excl = sdata[tid] - tsum;
    if (tid == 255) bsum[blockIdx.x] = sdata[255];
    int run = excl;
    #pragma unroll
    for (int i = 0; i < 4; ++i) {
        if (base + i < n) off[base + i] = run;
        run += v[i];
    }
}

// Single-block 128-thread exclusive scan of the block sums (nb <= 128).
__global__ void scan2_kernel(int* __restrict__ bsum, int nb) {
    __shared__ int s[128];
    int tid = threadIdx.x;
    int v = (tid < nb) ? bsum[tid] : 0;
    s[tid] = v;
    __syncthreads();
    for (int d = 1; d < 128; d <<= 1) {
        int t = (tid >= d) ? s[tid - d] : 0;
        __syncthreads();
        s[tid] += t;
        __syncthreads();
    }
    if (tid < nb) bsum[tid] = s[tid] - v;   // exclusive
}

// Adds block prefix; also seeds cur = off so scatter needs no off gather.
__global__ void scan3_kernel(int* __restrict__ off, int* __restrict__ cur,
                             const int* __restrict__ bsum, int n) {
    int i = blockIdx.x * blockDim.x + threadIdx.x;
    if (i < n) {
        int v = off[i] + bsum[i / SCAN_CHUNK];
        off[i] = v;
        cur[i] = v;
    }
}

// XCD-bound range scatter. Each block serves the dst range of its PHYSICAL
// XCD (s_getreg HW_REG_XCC_ID), pulling slice indices from a per-range
// ticket. All plain stores into range r's 1.2 MB pairs region thus come from
// one L2; NT edge-stream reads keep that region resident -> lines fill and
// write back whole. Correct under any block->XCD dispatch mapping.
__global__ void scatter_xcd_kernel(const int* __restrict__ esrc, const int* __restrict__ edst,
                                   const float* __restrict__ ew, int* __restrict__ cur,
                                   int2* __restrict__ pairs, int* __restrict__ ticket,
                                   int E, int chunk) {
    const int r = xcd_id();
    const int lo = r * RSIZE;
    const int hi = min(lo + RSIZE, N_NODES);
    __shared__ int s_sl;
    for (;;) {
        if (threadIdx.x == 0) s_sl = atomicAdd(&ticket[r], 1);
        __syncthreads();
        const int s = s_sl;
        __syncthreads();
        if (s >= SLICES) return;
        const int e0 = s * chunk;
        if (e0 >= E) continue;
        const int e1 = min(e0 + chunk, E);
        const int nv = (e1 - e0) >> 2;
        const vint4*   s4 = (const vint4*)(esrc + e0);
        const vint4*   d4 = (const vint4*)(edst + e0);
        const vfloat4* w4 = (const vfloat4*)(ew + e0);
        for (int i = threadIdx.x; i < nv; i += blockDim.x) {
            vint4 dd = __builtin_nontemporal_load(d4 + i);
            vint4 ss = __builtin_nontemporal_load(s4 + i);
            vfloat4 ww = __builtin_nontemporal_load(w4 + i);
            #pragma unroll
            for (int j = 0; j < 4; ++j) {
                int dj = dd[j];
                if (dj >= lo && dj < hi) {
                    int p = atomicAdd(&cur[dj], 1);   // cur seeded with off
                    int2 pr;
                    pr.x = ss[j];
                    pr.y = __float_as_int(ww[j]);
                    pairs[p] = pr;
                }
            }
        }
        for (int e = e0 + (nv << 2) + threadIdx.x; e < e1; e += blockDim.x) {
            int dj = edst[e];
            if (dj >= lo && dj < hi) {
                int p = atomicAdd(&cur[dj], 1);
                int2 pr;
                pr.x = esrc[e];
                pr.y = __float_as_int(ew[e]);
                pairs[p] = pr;
            }
        }
    }
}

// ---------------- SpMM: one wave per node, 8 edges in flight ----------------
// Oct o (lanes 8o..8o+7) processes edges k = o, o+8, ... Each lane loads
// row[ol] and row[ol+8] (2x float4 = 256 B/oct). Cross-oct sum via shfl_xor.
// y stored NT (written once; don't evict cached x rows).

__global__ void spmm_csr_kernel(const float* __restrict__ x,
                                const int2* __restrict__ pairs,
                                const int* __restrict__ off,
                                const int* __restrict__ deg,
                                float* __restrict__ y) {
    int gtid = blockIdx.x * blockDim.x + threadIdx.x;
    int node = gtid >> 6;
    int lane = threadIdx.x & 63;
    int o  = lane >> 3;    // oct 0..7 = which edge in the group of 8
    int ol = lane & 7;     // lane within oct
    if (node >= N_NODES) return;
    int s0 = off[node];
    int n  = deg[node];
    float4 a0 = make_float4(0.f, 0.f, 0.f, 0.f);
    float4 a1 = make_float4(0.f, 0.f, 0.f, 0.f);
    for (int k = o; k < n; k += 8) {
        int2 pr = pairs[s0 + k];                 // uniform within oct
        float w = __int_as_float(pr.y);
        const float4* row = (const float4*)(x + (size_t)pr.x * DIM);
        float4 v0 = row[ol];                     // dims [4ol, 4ol+4)
        float4 v1 = row[ol + 8];                 // dims [32+4ol, ...)
        a0.x += w * v0.x; a0.y += w * v0.y; a0.z += w * v0.z; a0.w += w * v0.w;
        a1.x += w * v1.x; a1.y += w * v1.y; a1.z += w * v1.z; a1.w += w * v1.w;
    }
    #pragma unroll
    for (int d = 8; d <= 32; d <<= 1) {
        a0.x += __shfl_xor(a0.x, d); a0.y += __shfl_xor(a0.y, d);
        a0.z += __shfl_xor(a0.z, d); a0.w += __shfl_xor(a0.w, d);
        a1.x += __shfl_xor(a1.x, d); a1.y += __shfl_xor(a1.y, d);
        a1.z += __shfl_xor(a1.z, d); a1.w += __shfl_xor(a1.w, d);
    }
    if (o == 0) {
        vfloat4* yrow = (vfloat4*)(y + (size_t)node * DIM);
        vfloat4 r0 = { a0.x, a0.y, a0.z, a0.w };
        vfloat4 r1 = { a1.x, a1.y, a1.z, a1.w };
        __builtin_nontemporal_store(r0, yrow + ol);
        __builtin_nontemporal_store(r1, yrow + ol + 8);
    }
}

// ---------------- fallback (atomic path, if ws too small) ----------------

__global__ void spmm_atomic_kernel(const float* __restrict__ x, const float* __restrict__ ew,
                                   const int* __restrict__ esrc, const int* __restrict__ edst,
                                   float* __restrict__ y, int n_edges) {
    long long tid = (long long)blockIdx.x * blockDim.x + threadIdx.x;
    int e = (int)(tid >> 6);
    int d = (int)(tid & 63);
    if (e >= n_edges) return;
    int s = esrc[e]; int t = edst[e]; float w = ew[e];
    atomicAdd(&y[(long long)t * DIM + d], w * x[(long long)s * DIM + d]);
}

extern "C" void kernel_launch(void* const* d_in, const int* in_sizes, int n_in,
                              void* d_out, int out_size, void* d_ws, size_t ws_size,
                              hipStream_t stream) {
    const float* emb  = (const float*)d_in[0];
    const float* ew   = (const float*)d_in[1];
    const int*   esrc = (const int*)d_in[2];
    const int*   edst = (const int*)d_in[3];
    float* out = (float*)d_out;

    const int E = in_sizes[1];
    const size_t layer_elems = (size_t)N_NODES * DIM;

    size_t need = (size_t)E * 8 + (size_t)3 * N_NODES * 4 + 1024;
    hipMemcpyAsync(out, emb, layer_elems * sizeof(float), hipMemcpyDeviceToDevice, stream);

    if (ws_size >= need) {
        char* w = (char*)d_ws;
        int2* pairs = (int2*)w;
        int* deg    = (int*)(w + (size_t)E * 8);
        int* cur    = deg + N_NODES;
        int* off    = cur + N_NODES;
        int* bsum   = off + N_NODES;     // 128 ints
        int* ticket = bsum + 128;        // NR ints

        hipMemsetAsync(deg, 0, (size_t)N_NODES * 4, stream);
        hipMemsetAsync(ticket, 0, NR * 4, stream);

        const int nv4 = E >> 2;
        hist_kernel<<<(nv4 + 255) / 256, 256, 0, stream>>>(edst, deg, E);

        const int nscan = (N_NODES + SCAN_CHUNK - 1) / SCAN_CHUNK;   // 98
        scan1_kernel<<<nscan, 256, 0, stream>>>(deg, off, bsum, N_NODES);
        scan2_kernel<<<1, 128, 0, stream>>>(bsum, nscan);
        scan3_kernel<<<(N_NODES + 255) / 256, 256, 0, stream>>>(off, cur, bsum, N_NODES);

        // slice size multiple of 4 so vector loads stay aligned
        const int chunk = (((E + SLICES - 1) / SLICES) + 3) & ~3;
        scatter_xcd_kernel<<<1024, 256, 0, stream>>>(esrc, edst, ew, cur, pairs, ticket, E, chunk);

        const int nb = (N_NODES + 3) / 4;   // 4 waves (nodes) per 256-thread block
        for (int l = 1; l <= 3; ++l) {
            spmm_csr_kernel<<<nb, 256, 0, stream>>>(
                out + (size_t)(l - 1) * layer_elems, pairs, off, deg,
                out + (size_t)l * layer_elems);
        }
    } else {
        hipMemsetAsync(out + layer_elems, 0, 3 * layer_elems * sizeof(float), stream);
        const long long total_threads = (long long)E * 64;
        const int blocks = (int)((total_threads + 255) / 256);
        for (int l = 1; l <= 3; ++l) {
            spmm_atomic_kernel<<<blocks, 256, 0, stream>>>(
                out + (size_t)(l - 1) * layer_elems, ew, esrc, edst,
                out + (size_t)l * layer_elems, E);
        }
    }
}